// Round 8
// baseline (445.608 us; speedup 1.0000x reference)
//
#include <hip/hip_runtime.h>
#include <hip/hip_fp16.h>

#define BB 4
#define CC 3
#define HH 384
#define WW 384
#define HW (HH * WW)
#define NP (BB * HW)
#define KK 5
#define K2 25
#define NITER 20
#define TT 24            // output tile (24x24); 384/24 = 16 tiles per dim
#define KF 4             // fused iterations per launch (5 launches x 4 = 20)
#define CR 40            // computed region rows/cols = TT + 4*KF
#define LR 44            // LDS rows = CR + 2+2 zero ring
#define RST 52           // LDS row stride floats (208 B; 52%32=20 -> 8 bank groups)
#define NTH 512
#define NACT 400         // active threads = CR * (CR/4)
#define TPR 10           // 4-px chunks per region row
#define IGRID 1024       // 16*16*4 blocks

static constexpr float INV_Z2 = 1.0f / (0.15f * 0.15f);

// ---------------------------------------------------------------------------
// R6 failed on resources, not on the idea: VGPR cap 128 vs ~160 live (spill),
// 96 KB LDS (1 block/CU), RST=72 bank conflicts (5.9M). R7 keeps the
// weights-in-registers KF-fusion but sized to fit:
//   - 4 px/thread -> W = 50 VGPRs, peak live ~110 < 128 (no spill at (512,4))
//   - img read direct from L1 (clamped+predicated float4), no img LDS stage
//   - LDS = x dbuf only, 18.3 KB, RST=52 (rows spread over 8 bank groups)
//   - TT=24, region 40x40 (+ring -> 44 rows), 400/512 active, 1024 blocks
// 5 dispatches, no prep kernel, zero weight memory traffic.
//
// Correctness:
//   - OOB taps: per-tap index predication -> exactly +0 (matches reference's
//     zero-padded unfold, where exp underflows to +0).
//   - Clamped img loads never fault; clamped (garbage) values only feed
//     predicated-to-zero taps; garbage is finite so 0*x stays 0.
//   - Halo: staged x true on radius 2*KF=8; wrongness creeps 2 px/sub-iter;
//     after 4 sub-iters the 24x24 tile is exact. Ring cells stay 0.
//   - Numerics = proven profile (absmax 0.0039): fp32 exp, unnormalized taps
//     rounded once to half, fp32 im = mask*(1/sz) applied per sub-iter.
// (R7 resubmission: prior bench was an infra failure, kernel unmeasured.)
// ---------------------------------------------------------------------------
__global__ __launch_bounds__(NTH, 4) void iter_tile(
    const float* __restrict__ img, const float* __restrict__ feat,
    const float* __restrict__ mask, const float* __restrict__ xin,
    float* __restrict__ xout, int first)
{
    __shared__ float buf[2][LR][RST];   // 18.3 KB

    const int tid = threadIdx.x;
    // XCD-chunked bijective swizzle (1024 % 8 == 0): stable producer=consumer
    const int lin = (blockIdx.x & 7) * (IGRID / 8) + (blockIdx.x >> 3);
    const int b  = lin >> 8;
    const int ty = (lin >> 4) & 15;
    const int tx = lin & 15;
    const int tr0 = ty * TT, tc0 = tx * TT;
    const size_t bHW = (size_t)b * HW;

    const bool act  = tid < NACT;
    const int row   = tid / TPR;            // 0..39 (+junk for tid>=400)
    const int chunk = tid - row * TPR;      // 0..9
    const int relrow = row - 8;             // -8..31
    const int relc0  = chunk * 4 - 8;       // -8..28, multiple of 4
    const int grow = tr0 + relrow;
    const int gcol = tc0 + relc0;
    const bool rowok = (unsigned)grow < HH;
    const bool colok = (unsigned)gcol <= (WW - 4);  // whole 4-chunk in image
    const int lrow = relrow + 10;           // 2..41
    const int lcol = relc0 + 12;            // 4..40 (16B-aligned)

    // ---- zero both buffers; ring cells are never written again -----------
    for (int i = tid; i < 2 * LR * RST; i += NTH)
        ((float*)buf)[i] = 0.f;
    __syncthreads();

    // ---- own mask and x stage (issued early; latency hides under weights)
    float4 mkv = make_float4(0.f, 0.f, 0.f, 0.f);
    float4 xv  = make_float4(0.f, 0.f, 0.f, 0.f);
    if (act && rowok && colok) {
        const size_t off = bHW + (size_t)grow * WW + gcol;
        mkv = *(const float4*)(mask + off);
        if (first) {
            float4 fv = *(const float4*)(feat + off);
            xv = make_float4(fv.x * mkv.x, fv.y * mkv.y,
                             fv.z * mkv.z, fv.w * mkv.w);
        } else {
            xv = *(const float4*)(xin + off);
        }
    }
    if (act) *(float4*)&buf[0][lrow][lcol] = xv;

    // ---- weights: 25 taps x 4 px -> 50 half2 registers, once per launch ---
    const float* imgb = img + (size_t)b * CC * HW;
    __half2 W[K2][2];
    float im[4] = {0.f, 0.f, 0.f, 0.f};
    if (act) {
        float vc[CC][4];
        {
            const int cg  = min(max(grow, 0), HH - 1);
            const int cc4 = min(max(gcol, 0), WW - 4);
            const int q0  = cg * WW + cc4;
#pragma unroll
            for (int c = 0; c < CC; ++c) {
                float4 v = *(const float4*)(imgb + c * HW + q0);
                vc[c][0] = v.x + 10.f; vc[c][1] = v.y + 10.f;
                vc[c][2] = v.z + 10.f; vc[c][3] = v.w + 10.f;
            }
        }
        float sz[4] = {1e-10f, 1e-10f, 1e-10f, 1e-10f};
#pragma unroll
        for (int dr = 0; dr < KK; ++dr) {
            const int gr  = grow + dr - 2;
            const bool rok = (unsigned)gr < HH;
            const int cg  = min(max(gr, 0), HH - 1);
            float wn[CC][12];
#pragma unroll
            for (int q = 0; q < 3; ++q) {
                const int c4  = gcol - 4 + 4 * q;
                const int cc4 = min(max(c4, 0), WW - 4);
                const int qo  = cg * WW + cc4;
#pragma unroll
                for (int c = 0; c < CC; ++c) {
                    float4 v = *(const float4*)(imgb + c * HW + qo);
                    wn[c][4 * q + 0] = v.x + 10.f; wn[c][4 * q + 1] = v.y + 10.f;
                    wn[c][4 * q + 2] = v.z + 10.f; wn[c][4 * q + 3] = v.w + 10.f;
                }
            }
#pragma unroll
            for (int dc = 0; dc < KK; ++dc) {
                const int t = dr * KK + dc;
                float av[4];
#pragma unroll
                for (int s = 0; s < 4; ++s) {
                    float d0 = wn[0][s + dc + 2] - vc[0][s];
                    float d1 = wn[1][s + dc + 2] - vc[1][s];
                    float d2 = wn[2][s + dc + 2] - vc[2][s];
                    float e2 = d0 * d0;
                    e2 = fmaf(d1, d1, e2);
                    e2 = fmaf(d2, d2, e2);
                    bool ok = rok && ((unsigned)(gcol + s + dc - 2) < WW);
                    av[s] = ok ? __expf(-e2 * INV_Z2) : 0.f;
                    sz[s] += av[s];
                }
                W[t][0] = __floats2half2_rn(av[0], av[1]);
                W[t][1] = __floats2half2_rn(av[2], av[3]);
            }
        }
        im[0] = mkv.x * (1.f / sz[0]);
        im[1] = mkv.y * (1.f / sz[1]);
        im[2] = mkv.z * (1.f / sz[2]);
        im[3] = mkv.w * (1.f / sz[3]);
    }
    __syncthreads();   // buf[0] fully staged

    // ---- KF sub-iterations, weights in registers --------------------------
    int cur = 0;
    float o[4] = {0.f, 0.f, 0.f, 0.f};
#pragma unroll 1
    for (int j = 0; j < KF; ++j) {
        if (act) {
            float acc[4] = {0.f, 0.f, 0.f, 0.f};
#pragma unroll
            for (int dr = 0; dr < KK; ++dr) {
                float xs[12];
#pragma unroll
                for (int q = 0; q < 3; ++q)
                    *(float4*)&xs[4 * q] =
                        *(const float4*)&buf[cur][lrow - 2 + dr][lcol - 4 + 4 * q];
#pragma unroll
                for (int dc = 0; dc < KK; ++dc) {
                    const int t = dr * KK + dc;
                    float2 w01 = __half22float2(W[t][0]);
                    float2 w23 = __half22float2(W[t][1]);
                    acc[0] = fmaf(w01.x, xs[dc + 2], acc[0]);
                    acc[1] = fmaf(w01.y, xs[dc + 3], acc[1]);
                    acc[2] = fmaf(w23.x, xs[dc + 4], acc[2]);
                    acc[3] = fmaf(w23.y, xs[dc + 5], acc[3]);
                }
            }
            o[0] = acc[0] * im[0]; o[1] = acc[1] * im[1];
            o[2] = acc[2] * im[2]; o[3] = acc[3] * im[3];
        }
        if (j < KF - 1) {
            if (act)
                *(float4*)&buf[cur ^ 1][lrow][lcol] =
                    make_float4(o[0], o[1], o[2], o[3]);
            cur ^= 1;
            __syncthreads();
        }
    }

    // ---- write back tile px (exact after KF sub-iters) --------------------
    if (act && (unsigned)relrow < TT && (unsigned)relc0 < TT) {
        float* dst = xout + bHW + (size_t)grow * WW + gcol;
        *(float4*)dst = make_float4(o[0], o[1], o[2], o[3]);
    }
}

extern "C" void kernel_launch(void* const* d_in, const int* in_sizes, int n_in,
                              void* d_out, int out_size, void* d_ws, size_t ws_size,
                              hipStream_t stream)
{
    const float* img  = (const float*)d_in[0];
    const float* feat = (const float*)d_in[1];
    const float* mask = (const float*)d_in[2];
    float* out = (float*)d_out;

    float* xa = (float*)d_ws;
    float* xb = xa + NP + 64;

    iter_tile<<<IGRID, NTH, 0, stream>>>(img, feat, mask, xa, xb, 1); // 1-4
    iter_tile<<<IGRID, NTH, 0, stream>>>(img, feat, mask, xb, xa, 0); // 5-8
    iter_tile<<<IGRID, NTH, 0, stream>>>(img, feat, mask, xa, xb, 0); // 9-12
    iter_tile<<<IGRID, NTH, 0, stream>>>(img, feat, mask, xb, xa, 0); // 13-16
    iter_tile<<<IGRID, NTH, 0, stream>>>(img, feat, mask, xa, out, 0);// 17-20
}

// Round 9
// 329.506 us; speedup vs baseline: 1.3524x; 1.3524x over previous
//
#include <hip/hip_runtime.h>
#include <hip/hip_fp16.h>

#define BB 4
#define CC 3
#define HH 384
#define WW 384
#define HW (HH * WW)
#define NP (BB * HW)
#define KK 5
#define K2 25
#define NITER 20
#define TT 24            // output tile (24x24); 384/24 = 16 tiles per dim
#define KF 4             // fused iterations per launch (5 launches x 4 = 20)
#define CR 40            // computed region rows/cols = TT + 4*KF
#define LR 44            // LDS rows = CR + 2+2 zero ring
#define RST 52           // LDS row stride floats (208 B, 16B-aligned)
#define NTH 512
#define NACT 400         // active threads = CR * (CR/4)
#define TPR 10           // 4-px chunks per region row
#define IGRID 1024       // 16*16*4 blocks

static constexpr float INV_Z2 = 1.0f / (0.15f * 0.15f);

// ---------------------------------------------------------------------------
// R7's counters: VGPR_Count=64 + WRITE_SIZE=138MB/dispatch = the W array
// spilled to scratch. Root cause: on this toolchain __launch_bounds__(N,w)
// caps VGPRs at 256/w, not 512/w (evidence: (512,2)->128 in R6, (512,4)->64
// in R7, (256,4)->64 in R4). Fix: w=2 -> cap 128 >= ~105 peak live.
// Also: weight phase accumulates e2[s][dc] channel-by-channel (wn_c 12 live
// instead of wn 36) -- same per-tap FP order (d0^2 then +d1^2 then +d2^2),
// bit-identical numerics, just lower register pressure.
// Everything else identical to R7 (which never ran un-spilled).
// ---------------------------------------------------------------------------
__global__ __launch_bounds__(NTH, 2) void iter_tile(
    const float* __restrict__ img, const float* __restrict__ feat,
    const float* __restrict__ mask, const float* __restrict__ xin,
    float* __restrict__ xout, int first)
{
    __shared__ float buf[2][LR][RST];   // 18.3 KB

    const int tid = threadIdx.x;
    // XCD-chunked bijective swizzle (1024 % 8 == 0): stable producer=consumer
    const int lin = (blockIdx.x & 7) * (IGRID / 8) + (blockIdx.x >> 3);
    const int b  = lin >> 8;
    const int ty = (lin >> 4) & 15;
    const int tx = lin & 15;
    const int tr0 = ty * TT, tc0 = tx * TT;
    const size_t bHW = (size_t)b * HW;

    const bool act  = tid < NACT;
    const int row   = tid / TPR;            // 0..39 (+junk for tid>=400)
    const int chunk = tid - row * TPR;      // 0..9
    const int relrow = row - 8;             // -8..31
    const int relc0  = chunk * 4 - 8;       // -8..28, multiple of 4
    const int grow = tr0 + relrow;
    const int gcol = tc0 + relc0;
    const bool rowok = (unsigned)grow < HH;
    const bool colok = (unsigned)gcol <= (WW - 4);  // whole 4-chunk in image
    const int lrow = relrow + 10;           // 2..41
    const int lcol = relc0 + 12;            // 4..40 (16B-aligned)

    // ---- zero both buffers; ring cells are never written again -----------
    for (int i = tid; i < 2 * LR * RST; i += NTH)
        ((float*)buf)[i] = 0.f;
    __syncthreads();

    // ---- own mask and x stage (issued early; latency hides under weights)
    float4 mkv = make_float4(0.f, 0.f, 0.f, 0.f);
    float4 xv  = make_float4(0.f, 0.f, 0.f, 0.f);
    if (act && rowok && colok) {
        const size_t off = bHW + (size_t)grow * WW + gcol;
        mkv = *(const float4*)(mask + off);
        if (first) {
            float4 fv = *(const float4*)(feat + off);
            xv = make_float4(fv.x * mkv.x, fv.y * mkv.y,
                             fv.z * mkv.z, fv.w * mkv.w);
        } else {
            xv = *(const float4*)(xin + off);
        }
    }
    if (act) *(float4*)&buf[0][lrow][lcol] = xv;

    // ---- weights: 25 taps x 4 px -> 50 half2 registers, once per launch ---
    const float* imgb = img + (size_t)b * CC * HW;
    __half2 W[K2][2];
    float im[4] = {0.f, 0.f, 0.f, 0.f};
    if (act) {
        float vc[CC][4];
        {
            const int cg  = min(max(grow, 0), HH - 1);
            const int cc4 = min(max(gcol, 0), WW - 4);
            const int q0  = cg * WW + cc4;
#pragma unroll
            for (int c = 0; c < CC; ++c) {
                float4 v = *(const float4*)(imgb + c * HW + q0);
                vc[c][0] = v.x + 10.f; vc[c][1] = v.y + 10.f;
                vc[c][2] = v.z + 10.f; vc[c][3] = v.w + 10.f;
            }
        }
        float sz[4] = {1e-10f, 1e-10f, 1e-10f, 1e-10f};
#pragma unroll
        for (int dr = 0; dr < KK; ++dr) {
            const int gr  = grow + dr - 2;
            const bool rok = (unsigned)gr < HH;
            const int cg  = min(max(gr, 0), HH - 1);
            // e2[s][dc], accumulated channel-by-channel (12 live wn regs,
            // not 36; same FP order per tap: d0^2 then +d1^2 then +d2^2)
            float e2[4][KK];
#pragma unroll
            for (int c = 0; c < CC; ++c) {
                float wn[12];
#pragma unroll
                for (int q = 0; q < 3; ++q) {
                    const int c4  = gcol - 4 + 4 * q;
                    const int cc4 = min(max(c4, 0), WW - 4);
                    float4 v = *(const float4*)(imgb + c * HW + cg * WW + cc4);
                    wn[4 * q + 0] = v.x + 10.f; wn[4 * q + 1] = v.y + 10.f;
                    wn[4 * q + 2] = v.z + 10.f; wn[4 * q + 3] = v.w + 10.f;
                }
#pragma unroll
                for (int dc = 0; dc < KK; ++dc)
#pragma unroll
                    for (int s = 0; s < 4; ++s) {
                        float d = wn[s + dc + 2] - vc[c][s];
                        e2[s][dc] = (c == 0) ? d * d : fmaf(d, d, e2[s][dc]);
                    }
            }
#pragma unroll
            for (int dc = 0; dc < KK; ++dc) {
                const int t = dr * KK + dc;
                float av[4];
#pragma unroll
                for (int s = 0; s < 4; ++s) {
                    bool ok = rok && ((unsigned)(gcol + s + dc - 2) < WW);
                    av[s] = ok ? __expf(-e2[s][dc] * INV_Z2) : 0.f;
                    sz[s] += av[s];
                }
                W[t][0] = __floats2half2_rn(av[0], av[1]);
                W[t][1] = __floats2half2_rn(av[2], av[3]);
            }
        }
        im[0] = mkv.x * (1.f / sz[0]);
        im[1] = mkv.y * (1.f / sz[1]);
        im[2] = mkv.z * (1.f / sz[2]);
        im[3] = mkv.w * (1.f / sz[3]);
    }
    __syncthreads();   // buf[0] fully staged

    // ---- KF sub-iterations, weights in registers --------------------------
    int cur = 0;
    float o[4] = {0.f, 0.f, 0.f, 0.f};
#pragma unroll 1
    for (int j = 0; j < KF; ++j) {
        if (act) {
            float acc[4] = {0.f, 0.f, 0.f, 0.f};
#pragma unroll
            for (int dr = 0; dr < KK; ++dr) {
                float xs[12];
#pragma unroll
                for (int q = 0; q < 3; ++q)
                    *(float4*)&xs[4 * q] =
                        *(const float4*)&buf[cur][lrow - 2 + dr][lcol - 4 + 4 * q];
#pragma unroll
                for (int dc = 0; dc < KK; ++dc) {
                    const int t = dr * KK + dc;
                    float2 w01 = __half22float2(W[t][0]);
                    float2 w23 = __half22float2(W[t][1]);
                    acc[0] = fmaf(w01.x, xs[dc + 2], acc[0]);
                    acc[1] = fmaf(w01.y, xs[dc + 3], acc[1]);
                    acc[2] = fmaf(w23.x, xs[dc + 4], acc[2]);
                    acc[3] = fmaf(w23.y, xs[dc + 5], acc[3]);
                }
            }
            o[0] = acc[0] * im[0]; o[1] = acc[1] * im[1];
            o[2] = acc[2] * im[2]; o[3] = acc[3] * im[3];
        }
        if (j < KF - 1) {
            if (act)
                *(float4*)&buf[cur ^ 1][lrow][lcol] =
                    make_float4(o[0], o[1], o[2], o[3]);
            cur ^= 1;
            __syncthreads();
        }
    }

    // ---- write back tile px (exact after KF sub-iters) --------------------
    if (act && (unsigned)relrow < TT && (unsigned)relc0 < TT) {
        float* dst = xout + bHW + (size_t)grow * WW + gcol;
        *(float4*)dst = make_float4(o[0], o[1], o[2], o[3]);
    }
}

extern "C" void kernel_launch(void* const* d_in, const int* in_sizes, int n_in,
                              void* d_out, int out_size, void* d_ws, size_t ws_size,
                              hipStream_t stream)
{
    const float* img  = (const float*)d_in[0];
    const float* feat = (const float*)d_in[1];
    const float* mask = (const float*)d_in[2];
    float* out = (float*)d_out;

    float* xa = (float*)d_ws;
    float* xb = xa + NP + 64;

    iter_tile<<<IGRID, NTH, 0, stream>>>(img, feat, mask, xa, xb, 1); // 1-4
    iter_tile<<<IGRID, NTH, 0, stream>>>(img, feat, mask, xb, xa, 0); // 5-8
    iter_tile<<<IGRID, NTH, 0, stream>>>(img, feat, mask, xa, xb, 0); // 9-12
    iter_tile<<<IGRID, NTH, 0, stream>>>(img, feat, mask, xb, xa, 0); // 13-16
    iter_tile<<<IGRID, NTH, 0, stream>>>(img, feat, mask, xa, out, 0);// 17-20
}

// Round 10
// 180.555 us; speedup vs baseline: 2.4680x; 1.8250x over previous
//
#include <hip/hip_runtime.h>
#include <hip/hip_fp16.h>

#define BB 4
#define CC 3
#define HH 384
#define WW 384
#define HW (HH * WW)
#define NP (BB * HW)
#define KK 5
#define RR 2
#define K2 25
#define NITER 20
#define TT 48            // output tile; 384/48 = 8 tiles/dim
#define KF 4             // fused iterations per launch (5 x 4 = 20)
#define LR 68            // LDS rows: region 64 + 2+2 zero ring
#define RST 72           // LDS row stride floats (288 B, 16B-aligned)
#define NTH 1024         // 64 rows x 16 chunks, 4 px/thread: exact region cover
#define IGRID 256        // 8*8 tiles * 4 batches = 1 block/CU
#define PGRID 1152
#define PCPX (PGRID / 8)
#define GUARDH 1024      // guard halves before planes (max back-reach 770)

static constexpr float INV_Z2 = 1.0f / (0.15f * 0.15f);

// ---------------------------------------------------------------------------
// R9 lesson: recomputing weights per launch = 1600 VALU/thread x 5 launches x
// 2.78 redundancy, latency-stalled -> 60us/dispatch. R5 lesson: re-READING
// planes per sub-iter = 210MB -> 25us/dispatch. R10: prep computes the 12
// symmetric unnormalized fp16 planes ONCE (R3's proven kernel, absmax
// 0.0039); each iter launch loads its thread's 25 taps ONCE into 50 half2
// registers (~52MB, XCD-L2-resident) and reuses them across KF=4 sub-iters.
// ---------------------------------------------------------------------------

// prep: 2 px/thread. a(p,q) is exactly symmetric in fp; center tap exactly 1.
// Stores 12 lex-positive UNnormalized planes (fp16, OOB taps exactly 0),
// invm = mask/sumz (fp32), and x0 = feat*mask.  [R3 kernel, verbatim]
__global__ __launch_bounds__(256) void prep_sym(
    const float* __restrict__ img, const float* __restrict__ feat,
    const float* __restrict__ mask, __half* __restrict__ planes,
    float* __restrict__ invm, float* __restrict__ x0)
{
    int sbid = (blockIdx.x & 7) * PCPX + (blockIdx.x >> 3);  // XCD-chunked
    int gid = sbid * 256 + threadIdx.x;
    int p0 = gid * 2;
    int b   = p0 / HW;
    int rem = p0 - b * HW;          // even
    int h   = rem / WW;
    int wc  = rem - h * WW;

    const float* imgb = img + (size_t)b * CC * HW;
    const size_t bHW = (size_t)b * HW;

    float2 f  = *(const float2*)(feat + bHW + rem);
    float2 mk = *(const float2*)(mask + bHW + rem);
    *(float2*)(x0 + bHW + rem) = make_float2(f.x * mk.x, f.y * mk.y);

    float v0[2], v1[2], v2[2];
#pragma unroll
    for (int s = 0; s < 2; ++s) {
        v0[s] = imgb[0 * HW + rem + s] + 10.f;
        v1[s] = imgb[1 * HW + rem + s] + 10.f;
        v2[s] = imgb[2 * HW + rem + s] + 10.f;
    }

    float a[2][K2];
    float sz[2] = {1e-10f, 1e-10f};
#pragma unroll
    for (int t = 0; t < K2; ++t) {
        int dr = t / KK - RR, dc = t % KK - RR;
        int rr = h + dr;
#pragma unroll
        for (int s = 0; s < 2; ++s) {
            int cc2 = wc + s + dc;
            float av = 0.f;
            if (rr >= 0 && rr < HH && cc2 >= 0 && cc2 < WW) {
                int q = rr * WW + cc2;
                float d0 = imgb[0 * HW + q] + 10.f - v0[s];
                float d1 = imgb[1 * HW + q] + 10.f - v1[s];
                float d2 = imgb[2 * HW + q] + 10.f - v2[s];
                av = __expf(-(d0 * d0 + d1 * d1 + d2 * d2) * INV_Z2);
            }
            a[s][t] = av;
            sz[s] += av;
        }
    }
    float i0 = 1.f / sz[0], i1 = 1.f / sz[1];
    *(float2*)(invm + bHW + rem) = make_float2(mk.x * i0, mk.y * i1);
#pragma unroll
    for (int t = 13; t < K2; ++t) {
        __half2 hv = __floats2half2_rn(a[0][t], a[1][t]);
        *(__half2*)(planes + (size_t)(t - 13) * NP + bHW + rem) = hv;
    }
}

// ---------------------------------------------------------------------------
// One launch = KF=4 sub-iterations. 1024 thr x 4 px cover the 64x64 region
// exactly (no inactive lanes). W[25] loaded once: own taps aligned half2x2,
// mirror taps via R3's shifted read + NaN-safe select (guard-backed).
// Halo: staged x true on radius 2*KF=8; tile exact after 4 sub-iters.
// ---------------------------------------------------------------------------
__global__ __launch_bounds__(NTH, 2) void iter4(
    const __half* __restrict__ planes, const float* __restrict__ invm,
    const float* __restrict__ xin, float* __restrict__ xout)
{
    __shared__ float buf[2][LR][RST];   // 39.2 KB

    const int tid = threadIdx.x;
    // XCD-chunked bijective swizzle; matches prep's pixel-chunk ownership
    const int lin = (blockIdx.x & 7) * (IGRID / 8) + (blockIdx.x >> 3);
    const int b  = lin >> 6;
    const int ty = (lin >> 3) & 7;
    const int tx = lin & 7;
    const int tr0 = ty * TT, tc0 = tx * TT;
    const size_t bHW = (size_t)b * HW;

    const int row    = tid >> 4;          // 0..63
    const int chunk  = tid & 15;          // 0..15
    const int relrow = row - 8;           // -8..55
    const int relc0  = chunk * 4 - 8;     // -8..52, multiple of 4
    const int grow = tr0 + relrow;
    const int gcol = tc0 + relc0;
    const bool inimg = ((unsigned)grow < HH) && ((unsigned)gcol <= (WW - 4));
    const int lrow = relrow + 10;         // 2..65
    const int lcol = relc0 + 12;          // 4..64 (16B-aligned)

    // zero both buffers (ring cells never rewritten)
    for (int i = tid; i < 2 * LR * RST; i += NTH)
        ((float*)buf)[i] = 0.f;
    __syncthreads();

    // stage own x + invm (predicated; OOB region px stay exactly 0)
    float4 xv = make_float4(0.f, 0.f, 0.f, 0.f);
    float4 iv = make_float4(0.f, 0.f, 0.f, 0.f);
    if (inimg) {
        const size_t off = bHW + (size_t)grow * WW + gcol;
        xv = *(const float4*)(xin + off);
        iv = *(const float4*)(invm + off);
    }
    *(float4*)&buf[0][lrow][lcol] = xv;

    // ---- load 25 taps x 4 px into 50 half2 registers, once per launch -----
    __half2 W[K2][2];
    const __half hz = __float2half(0.f);
    if (inimg) {
        const __half* plb = planes + bHW + (size_t)grow * WW + gcol;
        W[12][0] = __floats2half2_rn(1.f, 1.f);
        W[12][1] = __floats2half2_rn(1.f, 1.f);
#pragma unroll
        for (int u = 13; u < K2; ++u) {
            const int dur = u / KK - RR;     // 0..2
            const int duc = u % KK - RR;     // -2..2
            const __half* pl = plb + (size_t)(u - 13) * NP;
            // own tap (+d): aligned, stored-0 handles OOB neighbor
            W[u][0] = *(const __half2*)(pl);
            W[u][1] = *(const __half2*)(pl + 2);
            // mirror tap (-d): value lives at p-d; select 0 if p-d off-image
            const int shift = -(dur * WW + duc);
            const bool okr = (dur == 0) || (grow >= dur);
            __half m0 = (okr && (unsigned)(gcol + 0 - duc) < WW) ? pl[shift + 0] : hz;
            __half m1 = (okr && (unsigned)(gcol + 1 - duc) < WW) ? pl[shift + 1] : hz;
            __half m2 = (okr && (unsigned)(gcol + 2 - duc) < WW) ? pl[shift + 2] : hz;
            __half m3 = (okr && (unsigned)(gcol + 3 - duc) < WW) ? pl[shift + 3] : hz;
            W[24 - u][0] = __halves2half2(m0, m1);
            W[24 - u][1] = __halves2half2(m2, m3);
        }
    } else {
#pragma unroll
        for (int t = 0; t < K2; ++t) {
            W[t][0] = __halves2half2(hz, hz);
            W[t][1] = __halves2half2(hz, hz);
        }
    }
    __syncthreads();   // buf[0] fully staged

    // ---- KF sub-iterations, weights in registers --------------------------
    int cur = 0;
    float o[4] = {0.f, 0.f, 0.f, 0.f};
#pragma unroll 1
    for (int j = 0; j < KF; ++j) {
        float acc[4] = {0.f, 0.f, 0.f, 0.f};
#pragma unroll
        for (int dr = 0; dr < KK; ++dr) {
            float xs[12];
#pragma unroll
            for (int q = 0; q < 3; ++q)
                *(float4*)&xs[4 * q] =
                    *(const float4*)&buf[cur][lrow - 2 + dr][lcol - 4 + 4 * q];
#pragma unroll
            for (int dc = 0; dc < KK; ++dc) {
                const int t = dr * KK + dc;
                float2 w01 = __half22float2(W[t][0]);
                float2 w23 = __half22float2(W[t][1]);
                acc[0] = fmaf(w01.x, xs[dc + 2], acc[0]);
                acc[1] = fmaf(w01.y, xs[dc + 3], acc[1]);
                acc[2] = fmaf(w23.x, xs[dc + 4], acc[2]);
                acc[3] = fmaf(w23.y, xs[dc + 5], acc[3]);
            }
        }
        o[0] = acc[0] * iv.x; o[1] = acc[1] * iv.y;
        o[2] = acc[2] * iv.z; o[3] = acc[3] * iv.w;
        if (j < KF - 1) {
            *(float4*)&buf[cur ^ 1][lrow][lcol] =
                make_float4(o[0], o[1], o[2], o[3]);
            cur ^= 1;
            __syncthreads();
        }
    }

    // ---- write back tile px (exact after KF sub-iters; always in-image) ---
    if ((unsigned)relrow < TT && (unsigned)relc0 < TT) {
        float* dst = xout + bHW + (size_t)grow * WW + gcol;
        *(float4*)dst = make_float4(o[0], o[1], o[2], o[3]);
    }
}

extern "C" void kernel_launch(void* const* d_in, const int* in_sizes, int n_in,
                              void* d_out, int out_size, void* d_ws, size_t ws_size,
                              hipStream_t stream)
{
    const float* img  = (const float*)d_in[0];
    const float* feat = (const float*)d_in[1];
    const float* mask = (const float*)d_in[2];
    float* out = (float*)d_out;

    // ws: [ guard 2KB | planes 12*NP halves (14.2MB) | invm NP f32 | xa | xb ]
    __half* planes = (__half*)d_ws + GUARDH;
    float* invmp = (float*)(planes + (size_t)12 * NP);
    float* xa = invmp + NP;
    float* xb = xa + NP + 64;

    prep_sym<<<PGRID, 256, 0, stream>>>(img, feat, mask, planes, invmp, xa);
    iter4<<<IGRID, NTH, 0, stream>>>(planes, invmp, xa, xb);   // 1-4
    iter4<<<IGRID, NTH, 0, stream>>>(planes, invmp, xb, xa);   // 5-8
    iter4<<<IGRID, NTH, 0, stream>>>(planes, invmp, xa, xb);   // 9-12
    iter4<<<IGRID, NTH, 0, stream>>>(planes, invmp, xb, xa);   // 13-16
    iter4<<<IGRID, NTH, 0, stream>>>(planes, invmp, xa, out);  // 17-20
}

// Round 11
// 157.119 us; speedup vs baseline: 2.8361x; 1.1492x over previous
//
#include <hip/hip_runtime.h>
#include <hip/hip_fp16.h>

#define BB 4
#define CC 3
#define HH 384
#define WW 384
#define HW (HH * WW)
#define NP (BB * HW)
#define KK 5
#define RR 2
#define K2 25
#define NITER 20
#define TT 48            // output tile; 384/48 = 8 tiles/dim
#define KF 4             // fused iterations per launch (5 x 4 = 20)
#define LR 68            // LDS rows: region 64 + 2+2 zero ring
#define RSTH 80          // LDS row stride in HALVES (160 B)
#define NTH 1024         // 64 rows x 16 chunks, 4 px/thread: exact region cover
#define IGRID 256        // 8*8 tiles * 4 batches = 1 block/CU
#define PGRID 1152
#define PCPX (PGRID / 8)
#define GUARDH 1024      // guard halves before planes (max back-reach 770)

static constexpr float INV_Z2 = 1.0f / (0.15f * 0.15f);

// ---------------------------------------------------------------------------
// R10 landed 180us; per-CU math says iter4 (~22us) is LDS-pipe-bound: 16
// waves x 15 ds_read_b128 x 4 sub-iters ~ 11.5K cyc of serialized LDS per CU
// (a wave-wide b128 is structurally >=8 cyc; swizzle can't help, only fewer
// bytes can). R11: x lives in LDS as HALF -> 3x ds_read_b64 per row, bytes
// halved, LDS 39->22 KB. fp32 fma chain unchanged; cvt at boundaries.
// Precision: propagation is a contraction (normalized weights), 20 half-
// roundings add ~2e-3 abs; expect absmax ~0.006-0.012 (< 0.02 threshold).
// Everything else identical to R10.
// ---------------------------------------------------------------------------

// prep: 2 px/thread. a(p,q) exactly symmetric in fp; center tap exactly 1.
// Stores 12 lex-positive UNnormalized planes (fp16, OOB taps exactly 0),
// invm = mask/sumz (fp32), and x0 = feat*mask.  [R3 kernel, verbatim]
__global__ __launch_bounds__(256) void prep_sym(
    const float* __restrict__ img, const float* __restrict__ feat,
    const float* __restrict__ mask, __half* __restrict__ planes,
    float* __restrict__ invm, float* __restrict__ x0)
{
    int sbid = (blockIdx.x & 7) * PCPX + (blockIdx.x >> 3);  // XCD-chunked
    int gid = sbid * 256 + threadIdx.x;
    int p0 = gid * 2;
    int b   = p0 / HW;
    int rem = p0 - b * HW;          // even
    int h   = rem / WW;
    int wc  = rem - h * WW;

    const float* imgb = img + (size_t)b * CC * HW;
    const size_t bHW = (size_t)b * HW;

    float2 f  = *(const float2*)(feat + bHW + rem);
    float2 mk = *(const float2*)(mask + bHW + rem);
    *(float2*)(x0 + bHW + rem) = make_float2(f.x * mk.x, f.y * mk.y);

    float v0[2], v1[2], v2[2];
#pragma unroll
    for (int s = 0; s < 2; ++s) {
        v0[s] = imgb[0 * HW + rem + s] + 10.f;
        v1[s] = imgb[1 * HW + rem + s] + 10.f;
        v2[s] = imgb[2 * HW + rem + s] + 10.f;
    }

    float a[2][K2];
    float sz[2] = {1e-10f, 1e-10f};
#pragma unroll
    for (int t = 0; t < K2; ++t) {
        int dr = t / KK - RR, dc = t % KK - RR;
        int rr = h + dr;
#pragma unroll
        for (int s = 0; s < 2; ++s) {
            int cc2 = wc + s + dc;
            float av = 0.f;
            if (rr >= 0 && rr < HH && cc2 >= 0 && cc2 < WW) {
                int q = rr * WW + cc2;
                float d0 = imgb[0 * HW + q] + 10.f - v0[s];
                float d1 = imgb[1 * HW + q] + 10.f - v1[s];
                float d2 = imgb[2 * HW + q] + 10.f - v2[s];
                av = __expf(-(d0 * d0 + d1 * d1 + d2 * d2) * INV_Z2);
            }
            a[s][t] = av;
            sz[s] += av;
        }
    }
    float i0 = 1.f / sz[0], i1 = 1.f / sz[1];
    *(float2*)(invm + bHW + rem) = make_float2(mk.x * i0, mk.y * i1);
#pragma unroll
    for (int t = 13; t < K2; ++t) {
        __half2 hv = __floats2half2_rn(a[0][t], a[1][t]);
        *(__half2*)(planes + (size_t)(t - 13) * NP + bHW + rem) = hv;
    }
}

// ---------------------------------------------------------------------------
// One launch = KF=4 sub-iterations. 1024 thr x 4 px cover the 64x64 region
// exactly. W[25] loaded once into 50 half2 regs (own taps aligned b64,
// mirror taps via shifted read + NaN-safe select, guard-backed). x in LDS
// as HALF, double-buffered. Tile exact after 4 sub-iters (halo radius 8).
// ---------------------------------------------------------------------------
__global__ __launch_bounds__(NTH, 2) void iter4(
    const __half* __restrict__ planes, const float* __restrict__ invm,
    const float* __restrict__ xin, float* __restrict__ xout)
{
    __shared__ __half buf[2][LR][RSTH];   // 21.8 KB

    const int tid = threadIdx.x;
    // XCD-chunked bijective swizzle; matches prep's pixel-chunk ownership
    const int lin = (blockIdx.x & 7) * (IGRID / 8) + (blockIdx.x >> 3);
    const int b  = lin >> 6;
    const int ty = (lin >> 3) & 7;
    const int tx = lin & 7;
    const int tr0 = ty * TT, tc0 = tx * TT;
    const size_t bHW = (size_t)b * HW;

    const int row    = tid >> 4;          // 0..63
    const int chunk  = tid & 15;          // 0..15
    const int relrow = row - 8;           // -8..55
    const int relc0  = chunk * 4 - 8;     // -8..52, multiple of 4
    const int grow = tr0 + relrow;
    const int gcol = tc0 + relc0;
    const bool inimg = ((unsigned)grow < HH) && ((unsigned)gcol <= (WW - 4));
    const int lrow = relrow + 10;         // 2..65
    const int hc   = relc0 + 12;          // 4..64 halves (mult of 4, 8B-align)

    // zero both buffers (half2 zeros; ring cells never rewritten)
    for (int i = tid; i < LR * RSTH; i += NTH)
        ((unsigned*)buf)[i] = 0u;
    __syncthreads();

    // stage own x (fp32 global -> half LDS) + invm (predicated)
    float4 xv = make_float4(0.f, 0.f, 0.f, 0.f);
    float4 iv = make_float4(0.f, 0.f, 0.f, 0.f);
    if (inimg) {
        const size_t off = bHW + (size_t)grow * WW + gcol;
        xv = *(const float4*)(xin + off);
        iv = *(const float4*)(invm + off);
    }
    {
        union { uint2 u; __half2 h[2]; } st;
        st.h[0] = __floats2half2_rn(xv.x, xv.y);
        st.h[1] = __floats2half2_rn(xv.z, xv.w);
        *(uint2*)&buf[0][lrow][hc] = st.u;
    }

    // ---- load 25 taps x 4 px into 50 half2 registers, once per launch -----
    __half2 W[K2][2];
    const __half hz = __float2half(0.f);
    if (inimg) {
        const __half* plb = planes + bHW + (size_t)grow * WW + gcol;
        W[12][0] = __floats2half2_rn(1.f, 1.f);
        W[12][1] = __floats2half2_rn(1.f, 1.f);
#pragma unroll
        for (int u = 13; u < K2; ++u) {
            const int dur = u / KK - RR;     // 0..2
            const int duc = u % KK - RR;     // -2..2
            const __half* pl = plb + (size_t)(u - 13) * NP;
            // own tap (+d): one aligned b64; stored-0 handles OOB neighbor
            union { uint2 u2; __half2 h[2]; } ow;
            ow.u2 = *(const uint2*)pl;
            W[u][0] = ow.h[0];
            W[u][1] = ow.h[1];
            // mirror tap (-d): value lives at p-d; select 0 if p-d off-image
            const int shift = -(dur * WW + duc);
            const bool okr = (dur == 0) || (grow >= dur);
            __half m0 = (okr && (unsigned)(gcol + 0 - duc) < WW) ? pl[shift + 0] : hz;
            __half m1 = (okr && (unsigned)(gcol + 1 - duc) < WW) ? pl[shift + 1] : hz;
            __half m2 = (okr && (unsigned)(gcol + 2 - duc) < WW) ? pl[shift + 2] : hz;
            __half m3 = (okr && (unsigned)(gcol + 3 - duc) < WW) ? pl[shift + 3] : hz;
            W[24 - u][0] = __halves2half2(m0, m1);
            W[24 - u][1] = __halves2half2(m2, m3);
        }
    } else {
#pragma unroll
        for (int t = 0; t < K2; ++t) {
            W[t][0] = __halves2half2(hz, hz);
            W[t][1] = __halves2half2(hz, hz);
        }
    }
    __syncthreads();   // buf[0] fully staged

    // ---- KF sub-iterations, weights in registers, x in half LDS -----------
    int cur = 0;
    float o[4] = {0.f, 0.f, 0.f, 0.f};
#pragma unroll 1
    for (int j = 0; j < KF; ++j) {
        float acc[4] = {0.f, 0.f, 0.f, 0.f};
#pragma unroll
        for (int dr = 0; dr < KK; ++dr) {
            const __half* rp = &buf[cur][lrow - 2 + dr][hc - 4];
            union { uint2 u2; __half2 h[2]; } r0, r1, r2;
            r0.u2 = *(const uint2*)(rp);       // halves hc-4 .. hc-1
            r1.u2 = *(const uint2*)(rp + 4);   // hc   .. hc+3
            r2.u2 = *(const uint2*)(rp + 8);   // hc+4 .. hc+7
            float xs[12];
            float2 t2;
            t2 = __half22float2(r0.h[0]); xs[0]  = t2.x; xs[1]  = t2.y;
            t2 = __half22float2(r0.h[1]); xs[2]  = t2.x; xs[3]  = t2.y;
            t2 = __half22float2(r1.h[0]); xs[4]  = t2.x; xs[5]  = t2.y;
            t2 = __half22float2(r1.h[1]); xs[6]  = t2.x; xs[7]  = t2.y;
            t2 = __half22float2(r2.h[0]); xs[8]  = t2.x; xs[9]  = t2.y;
            t2 = __half22float2(r2.h[1]); xs[10] = t2.x; xs[11] = t2.y;
#pragma unroll
            for (int dc = 0; dc < KK; ++dc) {
                const int t = dr * KK + dc;
                float2 w01 = __half22float2(W[t][0]);
                float2 w23 = __half22float2(W[t][1]);
                acc[0] = fmaf(w01.x, xs[dc + 2], acc[0]);
                acc[1] = fmaf(w01.y, xs[dc + 3], acc[1]);
                acc[2] = fmaf(w23.x, xs[dc + 4], acc[2]);
                acc[3] = fmaf(w23.y, xs[dc + 5], acc[3]);
            }
        }
        o[0] = acc[0] * iv.x; o[1] = acc[1] * iv.y;
        o[2] = acc[2] * iv.z; o[3] = acc[3] * iv.w;
        if (j < KF - 1) {
            union { uint2 u; __half2 h[2]; } st;
            st.h[0] = __floats2half2_rn(o[0], o[1]);
            st.h[1] = __floats2half2_rn(o[2], o[3]);
            *(uint2*)&buf[cur ^ 1][lrow][hc] = st.u;
            cur ^= 1;
            __syncthreads();
        }
    }

    // ---- write back tile px (exact after KF sub-iters; always in-image) ---
    if ((unsigned)relrow < TT && (unsigned)relc0 < TT) {
        float* dst = xout + bHW + (size_t)grow * WW + gcol;
        *(float4*)dst = make_float4(o[0], o[1], o[2], o[3]);
    }
}

extern "C" void kernel_launch(void* const* d_in, const int* in_sizes, int n_in,
                              void* d_out, int out_size, void* d_ws, size_t ws_size,
                              hipStream_t stream)
{
    const float* img  = (const float*)d_in[0];
    const float* feat = (const float*)d_in[1];
    const float* mask = (const float*)d_in[2];
    float* out = (float*)d_out;

    // ws: [ guard 2KB | planes 12*NP halves (14.2MB) | invm NP f32 | xa | xb ]
    __half* planes = (__half*)d_ws + GUARDH;
    float* invmp = (float*)(planes + (size_t)12 * NP);
    float* xa = invmp + NP;
    float* xb = xa + NP + 64;

    prep_sym<<<PGRID, 256, 0, stream>>>(img, feat, mask, planes, invmp, xa);
    iter4<<<IGRID, NTH, 0, stream>>>(planes, invmp, xa, xb);   // 1-4
    iter4<<<IGRID, NTH, 0, stream>>>(planes, invmp, xb, xa);   // 5-8
    iter4<<<IGRID, NTH, 0, stream>>>(planes, invmp, xa, xb);   // 9-12
    iter4<<<IGRID, NTH, 0, stream>>>(planes, invmp, xb, xa);   // 13-16
    iter4<<<IGRID, NTH, 0, stream>>>(planes, invmp, xa, out);  // 17-20
}

// Round 13
// 131.641 us; speedup vs baseline: 3.3850x; 1.1935x over previous
//
#include <hip/hip_runtime.h>
#include <hip/hip_fp16.h>

#define BB 4
#define CC 3
#define HH 384
#define WW 384
#define HW (HH * WW)
#define NP (BB * HW)
#define KK 5
#define RR 2
#define K2 25
#define NITER 20
#define TT 48            // output tile; 384/48 = 8 tiles/dim
#define KF 4             // fused iterations per launch (5 x 4 = 20)
#define LR 68            // LDS rows: region 64 + 2+2 zero ring
#define RSTH 80          // LDS row stride in HALVES (160 B)
#define NTH 1024         // 64 rows x 16 chunks, 4 px/thread: exact region cover
#define IGRID 256        // 8*8 tiles * 4 batches = 1 block/CU
#define PGRID 1152
#define PCPX (PGRID / 8)
#define GUARDH 1024      // guard halves before planes (max back-reach 770)

static constexpr float INV_Z2 = 1.0f / (0.15f * 0.15f);

// ---------------------------------------------------------------------------
// R12 resubmission (prior round was an infra flake; kernel never ran —
// same signature as R7, whose identical resubmit then ran cleanly).
// R11 confirmed the LDS-byte model (157us). Budget: tax 46 (structural: KF>4
// hits the VGPR wall), prep ~13, iter4 ~19.6x5. R12 shaves the internals:
//  - shrink-region: sub-iter j guards compute/writes to radius 6-2j (stale
//    cells beyond are never read: sub-iter j+1 reads radius <= 6-2j).
//  - early-issue own-tap/x/invm global loads before LDS zero-fill (latency
//    hides under it); mirror loads overlap the pre-loop barrier.
//  - even-dc mirror taps (7/12) as 2x uint loads: 60 -> 46 VMEM inst/thread.
//  - prep: ~150 scalar img loads -> 45 clamped float2 loads (same per-tap
//    arithmetic and sz order -> numerics unchanged).
// ---------------------------------------------------------------------------

// prep: 2 px/thread. a(p,q) exactly symmetric in fp; center tap exactly 1.
// Stores 12 lex-positive UNnormalized planes (fp16, OOB taps exactly 0),
// invm = mask/sumz (fp32), and x0 = feat*mask. Vectorized img access:
// clamped float2 windows; clamped values only feed predicated-to-0 taps.
__global__ __launch_bounds__(256) void prep_sym(
    const float* __restrict__ img, const float* __restrict__ feat,
    const float* __restrict__ mask, __half* __restrict__ planes,
    float* __restrict__ invm, float* __restrict__ x0)
{
    int sbid = (blockIdx.x & 7) * PCPX + (blockIdx.x >> 3);  // XCD-chunked
    int gid = sbid * 256 + threadIdx.x;
    int p0 = gid * 2;
    int b   = p0 / HW;
    int rem = p0 - b * HW;          // even
    int h   = rem / WW;
    int wc  = rem - h * WW;

    const float* imgb = img + (size_t)b * CC * HW;
    const size_t bHW = (size_t)b * HW;

    float2 f  = *(const float2*)(feat + bHW + rem);
    float2 mk = *(const float2*)(mask + bHW + rem);
    *(float2*)(x0 + bHW + rem) = make_float2(f.x * mk.x, f.y * mk.y);

    // center values (own px), +10
    float v[CC][2];
#pragma unroll
    for (int c = 0; c < CC; ++c) {
        float2 cv = *(const float2*)(imgb + c * HW + rem);
        v[c][0] = cv.x + 10.f;
        v[c][1] = cv.y + 10.f;
    }

    float sz[2] = {1e-10f, 1e-10f};
#pragma unroll
    for (int dr = 0; dr < KK; ++dr) {
        const int rr  = h + dr - RR;
        const bool rok = (unsigned)rr < HH;
        const int rrc = min(max(rr, 0), HH - 1);
        // window cols wc-2..wc+3 via three clamped float2 loads per channel
        float xs[CC][6];
#pragma unroll
        for (int c = 0; c < CC; ++c) {
            const float* rowp = imgb + c * HW + rrc * WW;
            float2 A = *(const float2*)(rowp + max(wc - 2, 0));
            float2 Bv = *(const float2*)(rowp + wc);
            float2 Cv = *(const float2*)(rowp + min(wc + 2, WW - 2));
            xs[c][0] = A.x + 10.f;  xs[c][1] = A.y + 10.f;
            xs[c][2] = Bv.x + 10.f; xs[c][3] = Bv.y + 10.f;
            xs[c][4] = Cv.x + 10.f; xs[c][5] = Cv.y + 10.f;
        }
#pragma unroll
        for (int dc = 0; dc < KK; ++dc) {
            const int t = dr * KK + dc;
            float av[2];
#pragma unroll
            for (int s = 0; s < 2; ++s) {
                const int cc2 = wc + s + dc - RR;
                const bool ok = rok && ((unsigned)cc2 < WW);
                float d0 = xs[0][s + dc] - v[0][s];
                float d1 = xs[1][s + dc] - v[1][s];
                float d2 = xs[2][s + dc] - v[2][s];
                float e = d0 * d0 + d1 * d1 + d2 * d2;
                av[s] = ok ? __expf(-e * INV_Z2) : 0.f;
                sz[s] += av[s];
            }
            if (t >= 13) {
                __half2 hv = __floats2half2_rn(av[0], av[1]);
                *(__half2*)(planes + (size_t)(t - 13) * NP + bHW + rem) = hv;
            }
        }
    }
    float i0 = 1.f / sz[0], i1 = 1.f / sz[1];
    *(float2*)(invm + bHW + rem) = make_float2(mk.x * i0, mk.y * i1);
}

// ---------------------------------------------------------------------------
// One launch = KF=4 sub-iterations. 1024 thr x 4 px cover the 64x64 region
// exactly. W[25] in 50 half2 regs (own taps early-issued uint2, mirror taps
// shifted-read + NaN-safe select, guard-backed). x in half LDS, dbuf.
// Shrink-region: sub-iter j computes/writes only radius <= 6-2j.
// ---------------------------------------------------------------------------
__global__ __launch_bounds__(NTH, 2) void iter4(
    const __half* __restrict__ planes, const float* __restrict__ invm,
    const float* __restrict__ xin, float* __restrict__ xout)
{
    __shared__ __half buf[2][LR][RSTH];   // 21.8 KB

    const int tid = threadIdx.x;
    const int lin = (blockIdx.x & 7) * (IGRID / 8) + (blockIdx.x >> 3);
    const int b  = lin >> 6;
    const int ty = (lin >> 3) & 7;
    const int tx = lin & 7;
    const int tr0 = ty * TT, tc0 = tx * TT;
    const size_t bHW = (size_t)b * HW;

    const int row    = tid >> 4;          // 0..63
    const int chunk  = tid & 15;          // 0..15
    const int relrow = row - 8;           // -8..55
    const int relc0  = chunk * 4 - 8;     // -8..52, multiple of 4
    const int grow = tr0 + relrow;
    const int gcol = tc0 + relc0;
    const bool inimg = ((unsigned)grow < HH) && ((unsigned)gcol <= (WW - 4));
    const int lrow = relrow + 10;         // 2..65
    const int hc   = relc0 + 12;          // 4..64 halves (mult of 4, 8B-align)

    // ---- early-issue independent global loads (latency hides under zero) --
    uint2 own[12];
    float4 xv = make_float4(0.f, 0.f, 0.f, 0.f);
    float4 iv = make_float4(0.f, 0.f, 0.f, 0.f);
    const __half* plb = planes + bHW + (size_t)grow * WW + gcol;
    if (inimg) {
        const size_t off = bHW + (size_t)grow * WW + gcol;
        xv = *(const float4*)(xin + off);
        iv = *(const float4*)(invm + off);
#pragma unroll
        for (int u = 13; u < K2; ++u)
            own[u - 13] = *(const uint2*)(plb + (size_t)(u - 13) * NP);
    }

    // ---- zero both buffers (ring cells never rewritten) -------------------
    for (int i = tid; i < LR * RSTH; i += NTH)
        ((unsigned*)buf)[i] = 0u;
    __syncthreads();

    // stage own x (fp32 -> half LDS)
    {
        union { uint2 u; __half2 h[2]; } st;
        st.h[0] = __floats2half2_rn(xv.x, xv.y);
        st.h[1] = __floats2half2_rn(xv.z, xv.w);
        *(uint2*)&buf[0][lrow][hc] = st.u;
    }

    // ---- mirror loads + W pack (overlaps the barrier) ---------------------
    __half2 W[K2][2];
    const __half hz = __float2half(0.f);
    if (inimg) {
        W[12][0] = __floats2half2_rn(1.f, 1.f);
        W[12][1] = __floats2half2_rn(1.f, 1.f);
#pragma unroll
        for (int u = 13; u < K2; ++u) {
            const int dur = u / KK - RR;     // 0..2
            const int duc = u % KK - RR;     // -2..2
            const __half* pl = plb + (size_t)(u - 13) * NP;
            union { uint2 u2; __half2 h[2]; } ow;
            ow.u2 = own[u - 13];
            W[u][0] = ow.h[0];
            W[u][1] = ow.h[1];
            // mirror tap (-d): value at p-d; select 0 if p-d off-image
            const int shift = -(dur * WW + duc);
            const bool okr = (dur == 0) || (grow >= dur);
            __half m[4];
            if ((u % KK) % 2 == 0) {         // duc even: 4B-aligned pair loads
                union { unsigned u32; __half h[2]; } a0, a1;
                a0.u32 = *(const unsigned*)(pl + shift);
                a1.u32 = *(const unsigned*)(pl + shift + 2);
                m[0] = a0.h[0]; m[1] = a0.h[1];
                m[2] = a1.h[0]; m[3] = a1.h[1];
            } else {                          // duc odd: scalar halves
                m[0] = pl[shift + 0]; m[1] = pl[shift + 1];
                m[2] = pl[shift + 2]; m[3] = pl[shift + 3];
            }
#pragma unroll
            for (int k = 0; k < 4; ++k)
                if (!(okr && (unsigned)(gcol + k - duc) < WW)) m[k] = hz;
            W[24 - u][0] = __halves2half2(m[0], m[1]);
            W[24 - u][1] = __halves2half2(m[2], m[3]);
        }
    } else {
#pragma unroll
        for (int t = 0; t < K2; ++t) {
            W[t][0] = __halves2half2(hz, hz);
            W[t][1] = __halves2half2(hz, hz);
        }
    }
    __syncthreads();   // buf[0] fully staged

    // ---- KF sub-iterations, shrink-region guarded -------------------------
    int cur = 0;
    float o[4] = {0.f, 0.f, 0.f, 0.f};
#pragma unroll 1
    for (int j = 0; j < KF; ++j) {
        const int rj = 2 * (KF - 1 - j);            // 6,4,2,0
        const bool actj = (relrow >= -rj) && (relrow < TT + rj) &&
                          (relc0 + 3 >= -rj) && (relc0 < TT + rj);
        if (actj) {
            float acc[4] = {0.f, 0.f, 0.f, 0.f};
#pragma unroll
            for (int dr = 0; dr < KK; ++dr) {
                const __half* rp = &buf[cur][lrow - 2 + dr][hc - 4];
                union { uint2 u2; __half2 h[2]; } r0, r1, r2;
                r0.u2 = *(const uint2*)(rp);
                r1.u2 = *(const uint2*)(rp + 4);
                r2.u2 = *(const uint2*)(rp + 8);
                float xs[12];
                float2 t2;
                t2 = __half22float2(r0.h[0]); xs[0]  = t2.x; xs[1]  = t2.y;
                t2 = __half22float2(r0.h[1]); xs[2]  = t2.x; xs[3]  = t2.y;
                t2 = __half22float2(r1.h[0]); xs[4]  = t2.x; xs[5]  = t2.y;
                t2 = __half22float2(r1.h[1]); xs[6]  = t2.x; xs[7]  = t2.y;
                t2 = __half22float2(r2.h[0]); xs[8]  = t2.x; xs[9]  = t2.y;
                t2 = __half22float2(r2.h[1]); xs[10] = t2.x; xs[11] = t2.y;
#pragma unroll
                for (int dc = 0; dc < KK; ++dc) {
                    const int t = dr * KK + dc;
                    float2 w01 = __half22float2(W[t][0]);
                    float2 w23 = __half22float2(W[t][1]);
                    acc[0] = fmaf(w01.x, xs[dc + 2], acc[0]);
                    acc[1] = fmaf(w01.y, xs[dc + 3], acc[1]);
                    acc[2] = fmaf(w23.x, xs[dc + 4], acc[2]);
                    acc[3] = fmaf(w23.y, xs[dc + 5], acc[3]);
                }
            }
            o[0] = acc[0] * iv.x; o[1] = acc[1] * iv.y;
            o[2] = acc[2] * iv.z; o[3] = acc[3] * iv.w;
        }
        if (j < KF - 1) {
            if (actj) {
                union { uint2 u; __half2 h[2]; } st;
                st.h[0] = __floats2half2_rn(o[0], o[1]);
                st.h[1] = __floats2half2_rn(o[2], o[3]);
                *(uint2*)&buf[cur ^ 1][lrow][hc] = st.u;
            }
            cur ^= 1;
            __syncthreads();
        }
    }

    // ---- write back tile px (all tile px satisfy act at every j) ----------
    if ((unsigned)relrow < TT && (unsigned)relc0 < TT) {
        float* dst = xout + bHW + (size_t)grow * WW + gcol;
        *(float4*)dst = make_float4(o[0], o[1], o[2], o[3]);
    }
}

extern "C" void kernel_launch(void* const* d_in, const int* in_sizes, int n_in,
                              void* d_out, int out_size, void* d_ws, size_t ws_size,
                              hipStream_t stream)
{
    const float* img  = (const float*)d_in[0];
    const float* feat = (const float*)d_in[1];
    const float* mask = (const float*)d_in[2];
    float* out = (float*)d_out;

    // ws: [ guard 2KB | planes 12*NP halves (14.2MB) | invm NP f32 | xa | xb ]
    __half* planes = (__half*)d_ws + GUARDH;
    float* invmp = (float*)(planes + (size_t)12 * NP);
    float* xa = invmp + NP;
    float* xb = xa + NP + 64;

    prep_sym<<<PGRID, 256, 0, stream>>>(img, feat, mask, planes, invmp, xa);
    iter4<<<IGRID, NTH, 0, stream>>>(planes, invmp, xa, xb);   // 1-4
    iter4<<<IGRID, NTH, 0, stream>>>(planes, invmp, xb, xa);   // 5-8
    iter4<<<IGRID, NTH, 0, stream>>>(planes, invmp, xa, xb);   // 9-12
    iter4<<<IGRID, NTH, 0, stream>>>(planes, invmp, xb, xa);   // 13-16
    iter4<<<IGRID, NTH, 0, stream>>>(planes, invmp, xa, out);  // 17-20
}

// Round 14
// 128.224 us; speedup vs baseline: 3.4752x; 1.0267x over previous
//
#include <hip/hip_runtime.h>
#include <hip/hip_fp16.h>

#define BB 4
#define CC 3
#define HH 384
#define WW 384
#define HW (HH * WW)
#define NP (BB * HW)
#define KK 5
#define RR 2
#define K2 25
#define NITER 20
#define TT 48            // output tile; 384/48 = 8 tiles/dim
#define KF 4             // fused iterations per launch (5 x 4 = 20)
#define LR 68            // LDS rows: region 64 + 2+2 zero ring
#define RSTH 80          // LDS row stride in HALVES (160 B)
#define NTH 1024         // 64 rows x 16 chunks, 4 px/thread: exact region cover
#define IGRID 256        // 8*8 tiles * 4 batches = 1 block/CU
#define PGRID 1152
#define PCPX (PGRID / 8)
#define GUARDH 1024      // guard halves before planes (max back-reach 770)

static constexpr float INV_Z2 = 1.0f / (0.15f * 0.15f);

typedef _Float16 h2_t __attribute__((ext_vector_type(2)));

#if defined(__has_builtin)
#if __has_builtin(__builtin_amdgcn_fdot2)
#define USE_FDOT2 1
#endif
#endif

static __device__ __forceinline__ unsigned h2u(__half2 h) {
    union { __half2 h; unsigned u; } v; v.h = h; return v.u;
}
#ifdef USE_FDOT2
static __device__ __forceinline__ float fdot2f(unsigned w, unsigned x, float c) {
    union { unsigned u; h2_t h; } a, b; a.u = w; b.u = x;
    return __builtin_amdgcn_fdot2(a.h, b.h, c, false);
}
#endif

// ---------------------------------------------------------------------------
// R13 = 131.6us: tax 46 (6 dispatches, structural), prep ~7, iter4 ~15.6x5.
// iter4's sub-iter VALU is cvt-dominated: 50 loop-invariant W half2->float
// cvts re-done EVERY sub-iter (can't hoist: 100 f32 regs = R6 spill trap)
// + 12 xs cvts/row. R14: v_dot2_f32_f16 (fp16 mul, fp32 acc) -- repack W
// once per launch into tap-pair u32s Wp[px][dr][3] (60 regs, W's 50 die),
// xs rows consumed as raw u32 half-pairs (odd pairs via 1 alignbit each).
// Inner row: 12 dot2 + 4 alignbit vs ~52 cvt/fma. Numerics: exact fp16
// products, fp32 accumulate; only pairwise order changes. Singles pack
// (w, 0): 0 x finite xs = +0 exact.
// ---------------------------------------------------------------------------

// prep: 2 px/thread. a(p,q) exactly symmetric in fp; center tap exactly 1.
// Stores 12 lex-positive UNnormalized planes (fp16, OOB taps exactly 0),
// invm = mask/sumz (fp32), and x0 = feat*mask. Vectorized img access:
// clamped float2 windows; clamped values only feed predicated-to-0 taps.
__global__ __launch_bounds__(256) void prep_sym(
    const float* __restrict__ img, const float* __restrict__ feat,
    const float* __restrict__ mask, __half* __restrict__ planes,
    float* __restrict__ invm, float* __restrict__ x0)
{
    int sbid = (blockIdx.x & 7) * PCPX + (blockIdx.x >> 3);  // XCD-chunked
    int gid = sbid * 256 + threadIdx.x;
    int p0 = gid * 2;
    int b   = p0 / HW;
    int rem = p0 - b * HW;          // even
    int h   = rem / WW;
    int wc  = rem - h * WW;

    const float* imgb = img + (size_t)b * CC * HW;
    const size_t bHW = (size_t)b * HW;

    float2 f  = *(const float2*)(feat + bHW + rem);
    float2 mk = *(const float2*)(mask + bHW + rem);
    *(float2*)(x0 + bHW + rem) = make_float2(f.x * mk.x, f.y * mk.y);

    float v[CC][2];
#pragma unroll
    for (int c = 0; c < CC; ++c) {
        float2 cv = *(const float2*)(imgb + c * HW + rem);
        v[c][0] = cv.x + 10.f;
        v[c][1] = cv.y + 10.f;
    }

    float sz[2] = {1e-10f, 1e-10f};
#pragma unroll
    for (int dr = 0; dr < KK; ++dr) {
        const int rr  = h + dr - RR;
        const bool rok = (unsigned)rr < HH;
        const int rrc = min(max(rr, 0), HH - 1);
        float xs[CC][6];
#pragma unroll
        for (int c = 0; c < CC; ++c) {
            const float* rowp = imgb + c * HW + rrc * WW;
            float2 A = *(const float2*)(rowp + max(wc - 2, 0));
            float2 Bv = *(const float2*)(rowp + wc);
            float2 Cv = *(const float2*)(rowp + min(wc + 2, WW - 2));
            xs[c][0] = A.x + 10.f;  xs[c][1] = A.y + 10.f;
            xs[c][2] = Bv.x + 10.f; xs[c][3] = Bv.y + 10.f;
            xs[c][4] = Cv.x + 10.f; xs[c][5] = Cv.y + 10.f;
        }
#pragma unroll
        for (int dc = 0; dc < KK; ++dc) {
            const int t = dr * KK + dc;
            float av[2];
#pragma unroll
            for (int s = 0; s < 2; ++s) {
                const int cc2 = wc + s + dc - RR;
                const bool ok = rok && ((unsigned)cc2 < WW);
                float d0 = xs[0][s + dc] - v[0][s];
                float d1 = xs[1][s + dc] - v[1][s];
                float d2 = xs[2][s + dc] - v[2][s];
                float e = d0 * d0 + d1 * d1 + d2 * d2;
                av[s] = ok ? __expf(-e * INV_Z2) : 0.f;
                sz[s] += av[s];
            }
            if (t >= 13) {
                __half2 hv = __floats2half2_rn(av[0], av[1]);
                *(__half2*)(planes + (size_t)(t - 13) * NP + bHW + rem) = hv;
            }
        }
    }
    float i0 = 1.f / sz[0], i1 = 1.f / sz[1];
    *(float2*)(invm + bHW + rem) = make_float2(mk.x * i0, mk.y * i1);
}

// ---------------------------------------------------------------------------
// One launch = KF=4 sub-iterations. 1024 thr x 4 px cover the 64x64 region
// exactly. W loaded once (own taps early-issued uint2, mirror taps shifted-
// read + NaN-safe select), packed to tap-pair u32s for v_dot2_f32_f16.
// x in half LDS, dbuf. Shrink-region: sub-iter j guards radius 6-2j.
// ---------------------------------------------------------------------------
__global__ __launch_bounds__(NTH, 2) void iter4(
    const __half* __restrict__ planes, const float* __restrict__ invm,
    const float* __restrict__ xin, float* __restrict__ xout)
{
    __shared__ __half buf[2][LR][RSTH];   // 21.8 KB

    const int tid = threadIdx.x;
    const int lin = (blockIdx.x & 7) * (IGRID / 8) + (blockIdx.x >> 3);
    const int b  = lin >> 6;
    const int ty = (lin >> 3) & 7;
    const int tx = lin & 7;
    const int tr0 = ty * TT, tc0 = tx * TT;
    const size_t bHW = (size_t)b * HW;

    const int row    = tid >> 4;          // 0..63
    const int chunk  = tid & 15;          // 0..15
    const int relrow = row - 8;           // -8..55
    const int relc0  = chunk * 4 - 8;     // -8..52, multiple of 4
    const int grow = tr0 + relrow;
    const int gcol = tc0 + relc0;
    const bool inimg = ((unsigned)grow < HH) && ((unsigned)gcol <= (WW - 4));
    const int lrow = relrow + 10;         // 2..65
    const int hc   = relc0 + 12;          // 4..64 halves (mult of 4, 8B-align)

    // ---- early-issue independent global loads (latency hides under zero) --
    uint2 own[12];
    float4 xv = make_float4(0.f, 0.f, 0.f, 0.f);
    float4 iv = make_float4(0.f, 0.f, 0.f, 0.f);
    const __half* plb = planes + bHW + (size_t)grow * WW + gcol;
    if (inimg) {
        const size_t off = bHW + (size_t)grow * WW + gcol;
        xv = *(const float4*)(xin + off);
        iv = *(const float4*)(invm + off);
#pragma unroll
        for (int u = 13; u < K2; ++u)
            own[u - 13] = *(const uint2*)(plb + (size_t)(u - 13) * NP);
    }

    // ---- zero both buffers (ring cells never rewritten) -------------------
    for (int i = tid; i < LR * RSTH; i += NTH)
        ((unsigned*)buf)[i] = 0u;
    __syncthreads();

    // stage own x (fp32 -> half LDS)
    {
        union { uint2 u; __half2 h[2]; } st;
        st.h[0] = __floats2half2_rn(xv.x, xv.y);
        st.h[1] = __floats2half2_rn(xv.z, xv.w);
        *(uint2*)&buf[0][lrow][hc] = st.u;
    }

    // ---- mirror loads + W build (overlaps the barrier) --------------------
    __half2 W[K2][2];
    const __half hz = __float2half(0.f);
    if (inimg) {
        W[12][0] = __floats2half2_rn(1.f, 1.f);
        W[12][1] = __floats2half2_rn(1.f, 1.f);
#pragma unroll
        for (int u = 13; u < K2; ++u) {
            const int dur = u / KK - RR;     // 0..2
            const int duc = u % KK - RR;     // -2..2
            const __half* pl = plb + (size_t)(u - 13) * NP;
            union { uint2 u2; __half2 h[2]; } ow;
            ow.u2 = own[u - 13];
            W[u][0] = ow.h[0];
            W[u][1] = ow.h[1];
            // mirror tap (-d): value at p-d; select 0 if p-d off-image
            const int shift = -(dur * WW + duc);
            const bool okr = (dur == 0) || (grow >= dur);
            __half m[4];
            if ((u % KK) % 2 == 0) {         // duc even: 4B-aligned pair loads
                union { unsigned u32; __half h[2]; } a0, a1;
                a0.u32 = *(const unsigned*)(pl + shift);
                a1.u32 = *(const unsigned*)(pl + shift + 2);
                m[0] = a0.h[0]; m[1] = a0.h[1];
                m[2] = a1.h[0]; m[3] = a1.h[1];
            } else {                          // duc odd: scalar halves
                m[0] = pl[shift + 0]; m[1] = pl[shift + 1];
                m[2] = pl[shift + 2]; m[3] = pl[shift + 3];
            }
#pragma unroll
            for (int k = 0; k < 4; ++k)
                if (!(okr && (unsigned)(gcol + k - duc) < WW)) m[k] = hz;
            W[24 - u][0] = __halves2half2(m[0], m[1]);
            W[24 - u][1] = __halves2half2(m[2], m[3]);
        }
    } else {
#pragma unroll
        for (int t = 0; t < K2; ++t) {
            W[t][0] = __halves2half2(hz, hz);
            W[t][1] = __halves2half2(hz, hz);
        }
    }

#ifdef USE_FDOT2
    // ---- pack W into tap-pair u32s: Wp[px][dr][{dc01,dc23,dc4+zero}] ------
    unsigned Wp[4][KK][3];
#pragma unroll
    for (int dr = 0; dr < KK; ++dr) {
#pragma unroll
        for (int pc = 0; pc < 2; ++pc) {
            const int t0 = dr * KK + 2 * pc;
            unsigned a0 = h2u(W[t0][0]),     b0 = h2u(W[t0][1]);
            unsigned a1 = h2u(W[t0 + 1][0]), b1 = h2u(W[t0 + 1][1]);
            Wp[0][dr][pc] = (a0 & 0xFFFFu) | (a1 << 16);
            Wp[1][dr][pc] = (a0 >> 16)     | (a1 & 0xFFFF0000u);
            Wp[2][dr][pc] = (b0 & 0xFFFFu) | (b1 << 16);
            Wp[3][dr][pc] = (b0 >> 16)     | (b1 & 0xFFFF0000u);
        }
        unsigned a = h2u(W[dr * KK + 4][0]), bb = h2u(W[dr * KK + 4][1]);
        Wp[0][dr][2] = a & 0xFFFFu;
        Wp[1][dr][2] = a >> 16;
        Wp[2][dr][2] = bb & 0xFFFFu;
        Wp[3][dr][2] = bb >> 16;
    }
#endif
    __syncthreads();   // buf[0] fully staged

    // ---- KF sub-iterations, shrink-region guarded -------------------------
    int cur = 0;
    float o[4] = {0.f, 0.f, 0.f, 0.f};
#pragma unroll 1
    for (int j = 0; j < KF; ++j) {
        const int rj = 2 * (KF - 1 - j);            // 6,4,2,0
        const bool actj = (relrow >= -rj) && (relrow < TT + rj) &&
                          (relc0 + 3 >= -rj) && (relc0 < TT + rj);
        if (actj) {
            float acc[4] = {0.f, 0.f, 0.f, 0.f};
#pragma unroll
            for (int dr = 0; dr < KK; ++dr) {
                const __half* rp = &buf[cur][lrow - 2 + dr][hc - 4];
                uint2 q0 = *(const uint2*)(rp);        // halves hc-4..hc-1
                uint2 q1 = *(const uint2*)(rp + 4);    // hc  ..hc+3
                uint2 q2 = *(const uint2*)(rp + 8);    // hc+4..hc+7
#ifdef USE_FDOT2
                // raw half-pairs; xs local idx: u1=(2,3) u2=(4,5) u3=(6,7)
                // u4=(8,9); shifted sh_k = (2k+1, 2k+2)
                const unsigned u1 = q0.y, u2 = q1.x, u3 = q1.y,
                               u4 = q2.x, u5 = q2.y;
                const unsigned sh1 = (u1 >> 16) | (u2 << 16);
                const unsigned sh2 = (u2 >> 16) | (u3 << 16);
                const unsigned sh3 = (u3 >> 16) | (u4 << 16);
                const unsigned sh4 = (u4 >> 16) | (u5 << 16);
                acc[0] = fdot2f(Wp[0][dr][0], u1,  acc[0]);
                acc[0] = fdot2f(Wp[0][dr][1], u2,  acc[0]);
                acc[0] = fdot2f(Wp[0][dr][2], u3,  acc[0]);
                acc[1] = fdot2f(Wp[1][dr][0], sh1, acc[1]);
                acc[1] = fdot2f(Wp[1][dr][1], sh2, acc[1]);
                acc[1] = fdot2f(Wp[1][dr][2], sh3, acc[1]);
                acc[2] = fdot2f(Wp[2][dr][0], u2,  acc[2]);
                acc[2] = fdot2f(Wp[2][dr][1], u3,  acc[2]);
                acc[2] = fdot2f(Wp[2][dr][2], u4,  acc[2]);
                acc[3] = fdot2f(Wp[3][dr][0], sh2, acc[3]);
                acc[3] = fdot2f(Wp[3][dr][1], sh3, acc[3]);
                acc[3] = fdot2f(Wp[3][dr][2], sh4, acc[3]);
#else
                union { uint2 u2v; __half2 h[2]; } r0, r1, r2;
                r0.u2v = q0; r1.u2v = q1; r2.u2v = q2;
                float xs[12];
                float2 t2;
                t2 = __half22float2(r0.h[0]); xs[0]  = t2.x; xs[1]  = t2.y;
                t2 = __half22float2(r0.h[1]); xs[2]  = t2.x; xs[3]  = t2.y;
                t2 = __half22float2(r1.h[0]); xs[4]  = t2.x; xs[5]  = t2.y;
                t2 = __half22float2(r1.h[1]); xs[6]  = t2.x; xs[7]  = t2.y;
                t2 = __half22float2(r2.h[0]); xs[8]  = t2.x; xs[9]  = t2.y;
                t2 = __half22float2(r2.h[1]); xs[10] = t2.x; xs[11] = t2.y;
#pragma unroll
                for (int dc = 0; dc < KK; ++dc) {
                    const int t = dr * KK + dc;
                    float2 w01 = __half22float2(W[t][0]);
                    float2 w23 = __half22float2(W[t][1]);
                    acc[0] = fmaf(w01.x, xs[dc + 2], acc[0]);
                    acc[1] = fmaf(w01.y, xs[dc + 3], acc[1]);
                    acc[2] = fmaf(w23.x, xs[dc + 4], acc[2]);
                    acc[3] = fmaf(w23.y, xs[dc + 5], acc[3]);
                }
#endif
            }
            o[0] = acc[0] * iv.x; o[1] = acc[1] * iv.y;
            o[2] = acc[2] * iv.z; o[3] = acc[3] * iv.w;
        }
        if (j < KF - 1) {
            if (actj) {
                union { uint2 u; __half2 h[2]; } st;
                st.h[0] = __floats2half2_rn(o[0], o[1]);
                st.h[1] = __floats2half2_rn(o[2], o[3]);
                *(uint2*)&buf[cur ^ 1][lrow][hc] = st.u;
            }
            cur ^= 1;
            __syncthreads();
        }
    }

    // ---- write back tile px (all tile px satisfy act at every j) ----------
    if ((unsigned)relrow < TT && (unsigned)relc0 < TT) {
        float* dst = xout + bHW + (size_t)grow * WW + gcol;
        *(float4*)dst = make_float4(o[0], o[1], o[2], o[3]);
    }
}

extern "C" void kernel_launch(void* const* d_in, const int* in_sizes, int n_in,
                              void* d_out, int out_size, void* d_ws, size_t ws_size,
                              hipStream_t stream)
{
    const float* img  = (const float*)d_in[0];
    const float* feat = (const float*)d_in[1];
    const float* mask = (const float*)d_in[2];
    float* out = (float*)d_out;

    // ws: [ guard 2KB | planes 12*NP halves (14.2MB) | invm NP f32 | xa | xb ]
    __half* planes = (__half*)d_ws + GUARDH;
    float* invmp = (float*)(planes + (size_t)12 * NP);
    float* xa = invmp + NP;
    float* xb = xa + NP + 64;

    prep_sym<<<PGRID, 256, 0, stream>>>(img, feat, mask, planes, invmp, xa);
    iter4<<<IGRID, NTH, 0, stream>>>(planes, invmp, xa, xb);   // 1-4
    iter4<<<IGRID, NTH, 0, stream>>>(planes, invmp, xb, xa);   // 5-8
    iter4<<<IGRID, NTH, 0, stream>>>(planes, invmp, xa, xb);   // 9-12
    iter4<<<IGRID, NTH, 0, stream>>>(planes, invmp, xb, xa);   // 13-16
    iter4<<<IGRID, NTH, 0, stream>>>(planes, invmp, xa, out);  // 17-20
}